// Round 7
// baseline (799.052 us; speedup 1.0000x reference)
//
#include <hip/hip_runtime.h>
#include <cmath>

// ---------------------------------------------------------------------------
// 6x (conv3x3+BN+ReLU) -> LSTM(4096->256) over S=64 -> tanh(linear). fp32.
// R7: convs were LDS-throughput-bound (ds_read_b128 ~12cyc/CU; FMA:LDS was
// 13.7:1 vs the 24:1 balance point -- NOT register spill, R6 disproved that).
// Weights now come from global via wave-uniform scalar loads (readfirstlane-
// pinned base; oc-group constant per wave by construction), so LDS carries
// only window reads: FMA:LDS = 32..96 per layer -> VALU-bound. Small layers
// (8x8/16x16) get lane-level IC-split (ICS=2/4) + shfl_xor reduce to keep
// 64 wave-slots. No ic-chunking, no weight staging, single barrier.
// ---------------------------------------------------------------------------

__device__ __forceinline__ float sigmoidf_(float x) { return 1.f / (1.f + expf(-x)); }

// ---------------- fold BN into conv weights (all layers, one dispatch) -----
// wf layout: [ic][ky][OC][4]  (3 taps of row ky + pad, 16B-aligned per oc)
struct FoldPack {
  const float *w[6], *g[6], *b[6], *m[6], *v[6];
  float *wf[6], *bias[6];
  int oc[6], ic[6];
};

__global__ __launch_bounds__(256) void fold_all(FoldPack p) {
  const int layer = blockIdx.y;
  const int OC = p.oc[layer], IC = p.ic[layer];
  const int total = OC * IC * 9;
  const float* w = p.w[layer];
  float* wf = p.wf[layer];
  for (int i = blockIdx.x * 256 + threadIdx.x; i < total; i += gridDim.x * 256) {
    int oc = i / (IC * 9);
    int r  = i % (IC * 9);
    int ic = r / 9;
    int k  = r % 9;
    int ky = k / 3, kx = k % 3;
    float inv = p.g[layer][oc] / sqrtf(p.v[layer][oc] + 1e-5f);
    wf[(((ic * 3 + ky) * OC) + oc) * 4 + kx] = w[i] * inv;
  }
  if (blockIdx.x == 0) {
    int i = threadIdx.x;
    if (i < OC) {
      float inv = p.g[layer][i] / sqrtf(p.v[layer][i] + 1e-5f);
      p.bias[layer][i] = p.b[layer][i] - p.m[layer][i] * inv;
    }
  }
}

// ---------------- direct conv + bias + relu (R7) ----------------
// Thread mapping: tid = group*SLOT + icq*WPOS + worker, SLOT = WPOS*ICS a
// multiple of 64 so `group` (oc-tile) is wave-uniform -> weight loads are
// scalar (s_load) from global, cached in K$. LDS holds only the padded
// input image; windows read as aligned float4 (PIW = IW+4, xb mult of 4).
template<int IC, int OC, int IH, int IW, int STRIDE, int TPOS, int SPLITY, int ICS>
__global__ __launch_bounds__(256, 2) void conv_bn_relu(
    const float* __restrict__ in, const float* __restrict__ wf,
    const float* __restrict__ bias, float* __restrict__ out)
{
  constexpr int OH = IH / STRIDE, OW = IW / STRIDE;
  constexpr int OHB = OH / SPLITY;
  constexpr int RIH = (SPLITY == 1) ? (IH + 2) : ((OHB - 1) * STRIDE + 3);
  constexpr int PIW = IW + 4;
  constexpr int PLANE = RIH * PIW;
  constexpr int NPOS = OHB * OW;
  constexpr int WPOS = NPOS / TPOS;          // spatial workers
  constexpr int SLOT = WPOS * ICS;           // lanes per oc-group
  constexpr int GROUPS = 256 / SLOT;
  constexpr int TOC = OC / GROUPS;
  constexpr int CH = IC / ICS;               // ic's per lane-slice
  constexpr int SPAN = (TPOS - 1) * STRIDE + 3;
  constexpr int NW = (SPAN + 3) / 4;
  constexpr int XSLOTS = OW / TPOS;
  static_assert(SLOT % 64 == 0 && GROUPS * SLOT == 256 && GROUPS * TOC == OC, "tiling");

  __shared__ float s_in[IC * PLANE];

  const int tid = threadIdx.x;
  const int n     = (SPLITY == 1) ? blockIdx.x : blockIdx.x / SPLITY;
  const int split = (SPLITY == 1) ? 0 : blockIdx.x % SPLITY;
  const int ry0 = split * OHB;
  const int r0  = ry0 * STRIDE - 1;          // input row mapped to LDS row 0

  // zero LDS (vectorized; covers halo)
  for (int i = tid; i < IC * PLANE / 4; i += 256)
    ((float4*)s_in)[i] = float4{0.f, 0.f, 0.f, 0.f};
  __syncthreads();

  // stage interior rows; compile-time divisors, predicated edge rows
  constexpr int ROWF4 = IW / 4;
  constexpr int NSTG = IC * RIH * ROWF4;
  for (int i = tid; i < NSTG; i += 256) {
    int rw  = i % ROWF4;
    int t   = i / ROWF4;
    int row = t % RIH;
    int ic  = t / RIH;
    int giy = r0 + row;
    if (giy >= 0 && giy < IH) {
      float4 v = *(const float4*)(in + ((size_t)(n * IC + ic) * IH + giy) * IW + rw * 4);
      float* dst = &s_in[(ic * RIH + row) * PIW + 1 + rw * 4];
      dst[0] = v.x; dst[1] = v.y; dst[2] = v.z; dst[3] = v.w;
    }
  }
  __syncthreads();

  const int group  = tid / SLOT;             // wave-uniform (SLOT % 64 == 0)
  const int sl     = tid % SLOT;
  const int icq    = sl / WPOS;
  const int worker = sl % WPOS;
  const int oy  = worker / XSLOTS;
  const int ox0 = (worker % XSLOTS) * TPOS;
  const int xb  = ox0 * STRIDE;              // multiple of 4

  const int oc0u = __builtin_amdgcn_readfirstlane(group * TOC);
  const float4* wg = (const float4*)wf + oc0u;   // [ic][ky][OC] float4 view

  float acc[TOC][TPOS];
  #pragma unroll
  for (int a = 0; a < TOC; ++a)
    #pragma unroll
    for (int p = 0; p < TPOS; ++p) acc[a][p] = 0.f;

  for (int icl = 0; icl < CH; ++icl) {
    const int ic = icq * CH + icl;
    const float* sI = &s_in[ic * PLANE];
    #pragma unroll
    for (int ky = 0; ky < 3; ++ky) {
      float row[NW * 4];
      {
        const float4* rp = (const float4*)&sI[(oy * STRIDE + ky) * PIW + xb];
        #pragma unroll
        for (int w = 0; w < NW; ++w) {
          float4 t4 = rp[w];
          row[4*w+0] = t4.x; row[4*w+1] = t4.y;
          row[4*w+2] = t4.z; row[4*w+3] = t4.w;
        }
      }
      const float4* wrow = wg + (ic * 3 + ky) * OC;   // scalar addr when ICS==1
      #pragma unroll
      for (int oc = 0; oc < TOC; ++oc) {
        float4 w4 = wrow[oc];
        #pragma unroll
        for (int p = 0; p < TPOS; ++p)
          acc[oc][p] = fmaf(row[p * STRIDE + 0], w4.x,
                       fmaf(row[p * STRIDE + 1], w4.y,
                       fmaf(row[p * STRIDE + 2], w4.z, acc[oc][p])));
      }
    }
  }

  // reduce across ic-slices (lane xor within wave; SLOT==64 whenever ICS>1)
  #pragma unroll
  for (int d = WPOS; d < SLOT; d <<= 1)
    #pragma unroll
    for (int oc = 0; oc < TOC; ++oc)
      #pragma unroll
      for (int p = 0; p < TPOS; ++p)
        acc[oc][p] += __shfl_xor(acc[oc][p], d);

  if (icq == 0) {
    float* outN = out + (size_t)n * (OC * OH * OW);
    #pragma unroll
    for (int oc = 0; oc < TOC; ++oc) {
      const float bb = bias[oc0u + oc];
      float* op = outN + ((size_t)(oc0u + oc) * OH + (ry0 + oy)) * OW + ox0;
      if (TPOS >= 4) {
        #pragma unroll
        for (int vq = 0; vq < TPOS / 4; ++vq) {
          float4 val;
          val.x = fmaxf(acc[oc][vq*4+0] + bb, 0.f);
          val.y = fmaxf(acc[oc][vq*4+1] + bb, 0.f);
          val.z = fmaxf(acc[oc][vq*4+2] + bb, 0.f);
          val.w = fmaxf(acc[oc][vq*4+3] + bb, 0.f);
          *(float4*)(op + vq * 4) = val;
        }
      } else {
        float2 val;
        val.x = fmaxf(acc[oc][0] + bb, 0.f);
        val.y = fmaxf(acc[oc][1] + bb, 0.f);
        *(float2*)op = val;
      }
    }
  }
}

// ---------------- Xg partials: split-K GEMM ----------------
__global__ __launch_bounds__(256, 4) void gemm_xg(
    const float* __restrict__ feats, const float* __restrict__ w_ih,
    float* __restrict__ part)
{
  __shared__ float s_a[2][16][132];
  __shared__ float s_b[2][16][68];
  const int tid = threadIdx.x;
  const int col0 = blockIdx.x * 64;
  const int row0 = blockIdx.y * 128;
  const int kbase = blockIdx.z * 512;
  float* outp = part + (size_t)blockIdx.z * 1048576;

  const int lrowA = tid >> 1;
  const int kh = tid & 1;
  const int rA = row0 + lrowA;
  const int nA = (rA & 15) * 64 + (rA >> 4);
  const float* aptr = feats + (size_t)nA * 4096 + kbase + kh * 8;

  const int lrowB = tid >> 2;
  const int kq = tid & 3;
  const float* bptr = w_ih + (size_t)(col0 + lrowB) * 4096 + kbase + kq * 4;

  const int tr = tid >> 4;
  const int tc = tid & 15;

  float acc[8][4] = {};

  float4 a0 = *(const float4*)(aptr);
  float4 a1 = *(const float4*)(aptr + 4);
  float4 bv = *(const float4*)(bptr);
  {
    int ka = kh * 8;
    s_a[0][ka+0][lrowA] = a0.x; s_a[0][ka+1][lrowA] = a0.y;
    s_a[0][ka+2][lrowA] = a0.z; s_a[0][ka+3][lrowA] = a0.w;
    s_a[0][ka+4][lrowA] = a1.x; s_a[0][ka+5][lrowA] = a1.y;
    s_a[0][ka+6][lrowA] = a1.z; s_a[0][ka+7][lrowA] = a1.w;
    int kb = kq * 4;
    s_b[0][kb+0][lrowB] = bv.x; s_b[0][kb+1][lrowB] = bv.y;
    s_b[0][kb+2][lrowB] = bv.z; s_b[0][kb+3][lrowB] = bv.w;
  }
  __syncthreads();

  for (int kc = 0; kc < 32; ++kc) {
    const int cur = kc & 1;
    if (kc < 31) {
      a0 = *(const float4*)(aptr + (size_t)(kc + 1) * 16);
      a1 = *(const float4*)(aptr + (size_t)(kc + 1) * 16 + 4);
      bv = *(const float4*)(bptr + (size_t)(kc + 1) * 16);
    }
    #pragma unroll
    for (int k = 0; k < 16; ++k) {
      float4 x0 = *(const float4*)&s_a[cur][k][tr * 8];
      float4 x1 = *(const float4*)&s_a[cur][k][tr * 8 + 4];
      float4 y  = *(const float4*)&s_b[cur][k][tc * 4];
      float ar[8] = {x0.x, x0.y, x0.z, x0.w, x1.x, x1.y, x1.z, x1.w};
      float br[4] = {y.x, y.y, y.z, y.w};
      #pragma unroll
      for (int i = 0; i < 8; ++i)
        #pragma unroll
        for (int jj = 0; jj < 4; ++jj)
          acc[i][jj] = fmaf(ar[i], br[jj], acc[i][jj]);
    }
    if (kc < 31) {
      int nb = cur ^ 1;
      int ka = kh * 8;
      s_a[nb][ka+0][lrowA] = a0.x; s_a[nb][ka+1][lrowA] = a0.y;
      s_a[nb][ka+2][lrowA] = a0.z; s_a[nb][ka+3][lrowA] = a0.w;
      s_a[nb][ka+4][lrowA] = a1.x; s_a[nb][ka+5][lrowA] = a1.y;
      s_a[nb][ka+6][lrowA] = a1.z; s_a[nb][ka+7][lrowA] = a1.w;
      int kb = kq * 4;
      s_b[nb][kb+0][lrowB] = bv.x; s_b[nb][kb+1][lrowB] = bv.y;
      s_b[nb][kb+2][lrowB] = bv.z; s_b[nb][kb+3][lrowB] = bv.w;
    }
    __syncthreads();
  }

  #pragma unroll
  for (int i = 0; i < 8; ++i) {
    int rr = row0 + tr * 8 + i;
    float4 o;
    o.x = acc[i][0]; o.y = acc[i][1]; o.z = acc[i][2]; o.w = acc[i][3];
    *(float4*)(outp + (size_t)rr * 1024 + col0 + tc * 4) = o;
  }
}

// xg = sum_z p[z] + (b_ih + b_hh)
__global__ __launch_bounds__(256) void reduce_xg(
    const float* __restrict__ p, const float* __restrict__ b_ih,
    const float* __restrict__ b_hh, float* __restrict__ xg)
{
  int i = blockIdx.x * 256 + threadIdx.x;
  float4 s = {0.f, 0.f, 0.f, 0.f};
  #pragma unroll
  for (int z = 0; z < 8; ++z) {
    float4 a = ((const float4*)p)[(size_t)z * 262144 + i];
    s.x += a.x; s.y += a.y; s.z += a.z; s.w += a.w;
  }
  int cb = i & 255;
  float4 bi = ((const float4*)b_ih)[cb];
  float4 bh = ((const float4*)b_hh)[cb];
  float4 o;
  o.x = s.x + bi.x + bh.x;
  o.y = s.y + bi.y + bh.y;
  o.z = s.z + bi.z + bh.z;
  o.w = s.w + bi.w + bh.w;
  ((float4*)xg)[i] = o;
}

// ---------------- persistent LSTM recurrence ----------------
// 64 blocks x 1024 threads; (b = bid&15, g = bid>>4) so a batch's 4-block
// sync group shares bid%8 -> same XCD under cyclic dispatch. Tag-spin h
// exchange (correct for any placement).
__global__ __launch_bounds__(1024) void lstm_kernel(
    const float* __restrict__ xg, const float* __restrict__ w_hh,
    float* __restrict__ hs, unsigned long long* __restrict__ hpair)
{
  const int b = blockIdx.x & 15;
  const int g = blockIdx.x >> 4;
  const int tid = threadIdx.x;
  const int r = tid >> 2;
  const int q = tid & 3;
  const int gate = r >> 6;
  const int jl = r & 63;
  const int j = g * 64 + jl;

  float4 wv[16];
  {
    const float4* wrow = (const float4*)(w_hh + ((size_t)(gate * 256 + j)) * 256 + q * 64);
    #pragma unroll
    for (int k = 0; k < 16; ++k) wv[k] = wrow[k];
  }

  __shared__ float s_h[4 * 72];
  __shared__ float s_gates[4][64];
  float c_reg = 0.f;

  for (int s = 0; s < 64; ++s) {
    float xv = 0.f;
    if (q == 0) xv = xg[(size_t)(s * 16 + b) * 1024 + gate * 256 + j];
    float gv = 0.f;
    if (s > 0) {
      if (tid < 256) {
        const unsigned long long* src = hpair + ((size_t)(s - 1) * 16 + b) * 256 + tid;
        unsigned long long pv;
        do {
          pv = __hip_atomic_load(src, __ATOMIC_RELAXED, __HIP_MEMORY_SCOPE_AGENT);
        } while ((unsigned int)(pv >> 32) != (unsigned int)s);
        s_h[(tid >> 6) * 72 + (tid & 63)] = __uint_as_float((unsigned int)pv);
      }
      __syncthreads();
      const float4* hp = (const float4*)&s_h[q * 72];
      float p = 0.f;
      #pragma unroll
      for (int k = 0; k < 16; ++k) {
        float4 h4 = hp[k];
        p = fmaf(h4.x, wv[k].x, p);
        p = fmaf(h4.y, wv[k].y, p);
        p = fmaf(h4.z, wv[k].z, p);
        p = fmaf(h4.w, wv[k].w, p);
      }
      p += __shfl_xor(p, 1);
      p += __shfl_xor(p, 2);
      gv = p;
    }
    if (q == 0) s_gates[gate][jl] = gv + xv;
    __syncthreads();
    if (tid < 64) {
      float gi = s_gates[0][tid], gf = s_gates[1][tid];
      float gg = s_gates[2][tid], go = s_gates[3][tid];
      float cn = sigmoidf_(gf) * c_reg + sigmoidf_(gi) * tanhf(gg);
      c_reg = cn;
      float hv = sigmoidf_(go) * tanhf(cn);
      hs[(size_t)s * 4096 + b * 256 + g * 64 + tid] = hv;
      unsigned long long pv =
          ((unsigned long long)(unsigned int)(s + 1) << 32) | __float_as_uint(hv);
      __hip_atomic_store(hpair + ((size_t)s * 16 + b) * 256 + g * 64 + tid, pv,
                         __ATOMIC_RELAXED, __HIP_MEMORY_SCOPE_AGENT);
    }
  }
}

// ---------------- classifier head ----------------
__global__ __launch_bounds__(64) void cls_kernel(
    const float* __restrict__ hs, const float* __restrict__ cw,
    const float* __restrict__ cb, float* __restrict__ out)
{
  const int id = blockIdx.x;
  const int b = id / 53;
  const int t = id % 53;
  const int s = 11 + t;
  const int lane = threadIdx.x;
  float4 hv = ((const float4*)(hs + (size_t)s * 4096 + b * 256))[lane];
  float4 wv = ((const float4*)cw)[lane];
  float p = hv.x * wv.x + hv.y * wv.y + hv.z * wv.z + hv.w * wv.w;
  #pragma unroll
  for (int off = 32; off >= 1; off >>= 1) p += __shfl_xor(p, off);
  if (lane == 0) out[id] = tanhf(p + cb[0]);
}

// ---------------------------------------------------------------------------
extern "C" void kernel_launch(void* const* d_in, const int* in_sizes, int n_in,
                              void* d_out, int out_size, void* d_ws, size_t ws_size,
                              hipStream_t stream)
{
  (void)in_sizes; (void)n_in; (void)out_size; (void)ws_size;
  const float* imgs = (const float*)d_in[0];
  const float* w_ih  = (const float*)d_in[31];
  const float* w_hh  = (const float*)d_in[32];
  const float* b_ih  = (const float*)d_in[33];
  const float* b_hh  = (const float*)d_in[34];
  const float* cls_w = (const float*)d_in[35];
  const float* cls_b = (const float*)d_in[36];
  float* out = (float*)d_out;

  float* ws   = (float*)d_ws;
  float* actA = ws;
  float* actB = actA + 16777216;
  float* xg   = actB + 16777216;
  float* hs   = xg + 1048576;
  unsigned long long* hpair = (unsigned long long*)(hs + 262144);
  float* wfp  = hs + 262144 + 524288;
  static const int ocs[6] = {16, 16, 32, 32, 64, 64};
  static const int ics[6] = {3, 16, 16, 32, 32, 64};
  float* wf[6];
  size_t off = 0;
  for (int i = 0; i < 6; ++i) { wf[i] = wfp + off; off += (size_t)ocs[i] * ics[i] * 12; }
  float* biasp = wfp + off;
  float* bias[6];
  for (int i = 0; i < 6; ++i) bias[i] = biasp + i * 64;

  FoldPack fp;
  for (int i = 0; i < 6; ++i) {
    fp.w[i] = (const float*)d_in[1 + 5*i];
    fp.g[i] = (const float*)d_in[2 + 5*i];
    fp.b[i] = (const float*)d_in[3 + 5*i];
    fp.m[i] = (const float*)d_in[4 + 5*i];
    fp.v[i] = (const float*)d_in[5 + 5*i];
    fp.wf[i] = wf[i];
    fp.bias[i] = bias[i];
    fp.oc[i] = ocs[i];
    fp.ic[i] = ics[i];
  }
  fold_all<<<dim3(8, 6), 256, 0, stream>>>(fp);

  //                IC  OC  IH  IW  S  TP SPL ICS
  conv_bn_relu< 3, 16, 64, 64, 2,  8, 1, 1><<<1024, 256, 0, stream>>>(imgs,  wf[0], bias[0], actA);
  conv_bn_relu<16, 16, 32, 32, 1,  8, 2, 1><<<2048, 256, 0, stream>>>(actA, wf[1], bias[1], actB);
  conv_bn_relu<16, 32, 32, 32, 2,  4, 1, 1><<<1024, 256, 0, stream>>>(actB, wf[2], bias[2], actA);
  conv_bn_relu<32, 32, 16, 16, 1,  4, 1, 1><<<1024, 256, 0, stream>>>(actA, wf[3], bias[3], actB);
  conv_bn_relu<32, 64, 16, 16, 2,  2, 1, 2><<<1024, 256, 0, stream>>>(actB, wf[4], bias[4], actA);
  conv_bn_relu<64, 64,  8,  8, 1,  4, 1, 4><<<1024, 256, 0, stream>>>(actA, wf[5], bias[5], actB);

  gemm_xg<<<dim3(16, 8, 8), 256, 0, stream>>>(actB, w_ih, actA);
  reduce_xg<<<1024, 256, 0, stream>>>(actA, b_ih, b_hh, xg);
  lstm_kernel<<<64, 1024, 0, stream>>>(xg, w_hh, hs, hpair);
  cls_kernel<<<848, 64, 0, stream>>>(hs, cls_w, cls_b, out);
}

// Round 8
// 706.406 us; speedup vs baseline: 1.1312x; 1.1312x over previous
//
#include <hip/hip_runtime.h>
#include <cmath>

// ---------------------------------------------------------------------------
// 6x (conv3x3+BN+ReLU) -> LSTM(4096->256) over S=64 -> tanh(linear).
// R8: gemm_xg replaced by bf16 split-MFMA (a = ah + al, each bf16; 3 MFMA
// streams hh+hl+lh; residual ~2^-18/term -> absmax ~1e-5, threshold 1.3e-4).
// Convs: L0/L1 retiled for 4 blocks/CU + small acc (L0 was likely spilling:
// row[20]+acc[64] > 128-VGPR cap), L3 -> 3 blocks/CU. L2/L4/L5 unchanged.
// fp32 VALU caps convs at ~128us floor; MFMA machinery validated here on the
// GEMM shape first, conv port next round.
// ---------------------------------------------------------------------------

typedef __attribute__((ext_vector_type(8))) __bf16 bf16x8;
typedef __attribute__((ext_vector_type(4))) float f32x4;

__device__ __forceinline__ float sigmoidf_(float x) { return 1.f / (1.f + expf(-x)); }

__device__ __forceinline__ unsigned short f2bf(float f) {   // RNE
  unsigned u = __float_as_uint(f);
  unsigned r = (u + 0x7fffu + ((u >> 16) & 1u)) >> 16;
  return (unsigned short)r;
}
__device__ __forceinline__ float bf2f(unsigned short h) {
  return __uint_as_float(((unsigned)h) << 16);
}

// ---------------- fold BN into conv weights (one dispatch) ----------------
// wf layout: [ic][ky][OC][4]
struct FoldPack {
  const float *w[6], *g[6], *b[6], *m[6], *v[6];
  float *wf[6], *bias[6];
  int oc[6], ic[6];
};

__global__ __launch_bounds__(256) void fold_all(FoldPack p) {
  const int layer = blockIdx.y;
  const int OC = p.oc[layer], IC = p.ic[layer];
  const int total = OC * IC * 9;
  const float* w = p.w[layer];
  float* wf = p.wf[layer];
  for (int i = blockIdx.x * 256 + threadIdx.x; i < total; i += gridDim.x * 256) {
    int oc = i / (IC * 9);
    int r  = i % (IC * 9);
    int ic = r / 9;
    int k  = r % 9;
    int ky = k / 3, kx = k % 3;
    float inv = p.g[layer][oc] / sqrtf(p.v[layer][oc] + 1e-5f);
    wf[(((ic * 3 + ky) * OC) + oc) * 4 + kx] = w[i] * inv;
  }
  if (blockIdx.x == 0) {
    int i = threadIdx.x;
    if (i < OC) {
      float inv = p.g[layer][i] / sqrtf(p.v[layer][i] + 1e-5f);
      p.bias[layer][i] = p.b[layer][i] - p.m[layer][i] * inv;
    }
  }
}

// ---------------- direct conv + bias + relu ----------------
template<int IC, int OC, int IH, int IW, int STRIDE, int TPOS, int SPLITY,
         int ICS, int MINW>
__global__ __launch_bounds__(256, MINW) void conv_bn_relu(
    const float* __restrict__ in, const float* __restrict__ wf,
    const float* __restrict__ bias, float* __restrict__ out)
{
  constexpr int OH = IH / STRIDE, OW = IW / STRIDE;
  constexpr int OHB = OH / SPLITY;
  constexpr int RIH = (SPLITY == 1) ? (IH + 2) : ((OHB - 1) * STRIDE + 3);
  constexpr int PIW = IW + 4;
  constexpr int PLANE = RIH * PIW;
  constexpr int NPOS = OHB * OW;
  constexpr int WPOS = NPOS / TPOS;
  constexpr int SLOT = WPOS * ICS;
  constexpr int GROUPS = 256 / SLOT;
  constexpr int TOC = OC / GROUPS;
  constexpr int CH = IC / ICS;
  constexpr int SPAN = (TPOS - 1) * STRIDE + 3;
  constexpr int NW = (SPAN + 3) / 4;
  constexpr int XSLOTS = OW / TPOS;
  static_assert(SLOT % 64 == 0 && GROUPS * SLOT == 256 && GROUPS * TOC == OC, "tiling");

  __shared__ float s_in[IC * PLANE];

  const int tid = threadIdx.x;
  const int n     = (SPLITY == 1) ? blockIdx.x : blockIdx.x / SPLITY;
  const int split = (SPLITY == 1) ? 0 : blockIdx.x % SPLITY;
  const int ry0 = split * OHB;
  const int r0  = ry0 * STRIDE - 1;

  for (int i = tid; i < IC * PLANE / 4; i += 256)
    ((float4*)s_in)[i] = float4{0.f, 0.f, 0.f, 0.f};
  __syncthreads();

  constexpr int ROWF4 = IW / 4;
  constexpr int NSTG = IC * RIH * ROWF4;
  for (int i = tid; i < NSTG; i += 256) {
    int rw  = i % ROWF4;
    int t   = i / ROWF4;
    int row = t % RIH;
    int ic  = t / RIH;
    int giy = r0 + row;
    if (giy >= 0 && giy < IH) {
      float4 v = *(const float4*)(in + ((size_t)(n * IC + ic) * IH + giy) * IW + rw * 4);
      float* dst = &s_in[(ic * RIH + row) * PIW + 1 + rw * 4];
      dst[0] = v.x; dst[1] = v.y; dst[2] = v.z; dst[3] = v.w;
    }
  }
  __syncthreads();

  const int group  = tid / SLOT;             // wave-uniform
  const int sl     = tid % SLOT;
  const int icq    = sl / WPOS;
  const int worker = sl % WPOS;
  const int oy  = worker / XSLOTS;
  const int ox0 = (worker % XSLOTS) * TPOS;
  const int xb  = ox0 * STRIDE;

  const int oc0u = __builtin_amdgcn_readfirstlane(group * TOC);
  const float4* wg = (const float4*)wf + oc0u;

  float acc[TOC][TPOS];
  #pragma unroll
  for (int a = 0; a < TOC; ++a)
    #pragma unroll
    for (int p = 0; p < TPOS; ++p) acc[a][p] = 0.f;

  for (int icl = 0; icl < CH; ++icl) {
    const int ic = icq * CH + icl;
    const float* sI = &s_in[ic * PLANE];
    #pragma unroll
    for (int ky = 0; ky < 3; ++ky) {
      float row[NW * 4];
      {
        const float4* rp = (const float4*)&sI[(oy * STRIDE + ky) * PIW + xb];
        #pragma unroll
        for (int w = 0; w < NW; ++w) {
          float4 t4 = rp[w];
          row[4*w+0] = t4.x; row[4*w+1] = t4.y;
          row[4*w+2] = t4.z; row[4*w+3] = t4.w;
        }
      }
      const float4* wrow = wg + (ic * 3 + ky) * OC;
      #pragma unroll
      for (int oc = 0; oc < TOC; ++oc) {
        float4 w4 = wrow[oc];
        #pragma unroll
        for (int p = 0; p < TPOS; ++p)
          acc[oc][p] = fmaf(row[p * STRIDE + 0], w4.x,
                       fmaf(row[p * STRIDE + 1], w4.y,
                       fmaf(row[p * STRIDE + 2], w4.z, acc[oc][p])));
      }
    }
  }

  #pragma unroll
  for (int d = WPOS; d < SLOT; d <<= 1)
    #pragma unroll
    for (int oc = 0; oc < TOC; ++oc)
      #pragma unroll
      for (int p = 0; p < TPOS; ++p)
        acc[oc][p] += __shfl_xor(acc[oc][p], d);

  if (icq == 0) {
    float* outN = out + (size_t)n * (OC * OH * OW);
    #pragma unroll
    for (int oc = 0; oc < TOC; ++oc) {
      const float bb = bias[oc0u + oc];
      float* op = outN + ((size_t)(oc0u + oc) * OH + (ry0 + oy)) * OW + ox0;
      if (TPOS >= 4) {
        #pragma unroll
        for (int vq = 0; vq < TPOS / 4; ++vq) {
          float4 val;
          val.x = fmaxf(acc[oc][vq*4+0] + bb, 0.f);
          val.y = fmaxf(acc[oc][vq*4+1] + bb, 0.f);
          val.z = fmaxf(acc[oc][vq*4+2] + bb, 0.f);
          val.w = fmaxf(acc[oc][vq*4+3] + bb, 0.f);
          *(float4*)(op + vq * 4) = val;
        }
      } else {
        float2 val;
        val.x = fmaxf(acc[oc][0] + bb, 0.f);
        val.y = fmaxf(acc[oc][1] + bb, 0.f);
        *(float2*)op = val;
      }
    }
  }
}

// ---------------- bf16 hi/lo split prepass ----------------
// A (feats): remap image row n -> xg row r = (n%64)*16 + n/64.
__global__ __launch_bounds__(256) void split_a(
    const float* __restrict__ feats, unsigned short* __restrict__ ah,
    unsigned short* __restrict__ al)
{
  int i4 = blockIdx.x * 256 + threadIdx.x;    // float4 idx, 1,048,576 total
  int e = i4 * 4;
  int n = e >> 12;
  int k = e & 4095;
  int r = (n & 63) * 16 + (n >> 6);
  float4 v = ((const float4*)feats)[i4];
  ushort4 h, l;
  h.x = f2bf(v.x); l.x = f2bf(v.x - bf2f(h.x));
  h.y = f2bf(v.y); l.y = f2bf(v.y - bf2f(h.y));
  h.z = f2bf(v.z); l.z = f2bf(v.z - bf2f(h.z));
  h.w = f2bf(v.w); l.w = f2bf(v.w - bf2f(h.w));
  *(ushort4*)(ah + (size_t)r * 4096 + k) = h;
  *(ushort4*)(al + (size_t)r * 4096 + k) = l;
}

__global__ __launch_bounds__(256) void split_b(
    const float* __restrict__ w_ih, unsigned short* __restrict__ bh,
    unsigned short* __restrict__ bl)
{
  int i4 = blockIdx.x * 256 + threadIdx.x;
  float4 v = ((const float4*)w_ih)[i4];
  ushort4 h, l;
  h.x = f2bf(v.x); l.x = f2bf(v.x - bf2f(h.x));
  h.y = f2bf(v.y); l.y = f2bf(v.y - bf2f(h.y));
  h.z = f2bf(v.z); l.z = f2bf(v.z - bf2f(h.z));
  h.w = f2bf(v.w); l.w = f2bf(v.w - bf2f(h.w));
  ((ushort4*)bh)[i4] = h;
  ((ushort4*)bl)[i4] = l;
}

// ---------------- Xg partials: bf16 split-MFMA GEMM ----------------
// M=N=1024, K=4096 in 8 slices of 512. Block = 128x128 C-tile, 4 waves in
// 2x2, wave-tile 64x64 (16 16x16 frags). 3 MFMA streams: ah*bh + ah*bl +
// al*bh (al*bl ~ 2^-18, dropped). LDS rows stride 40 bf16 (80 B) -> 2-way
// bank pattern (free). grid (8,8,8) = 512 blocks, 2/CU.
__global__ __launch_bounds__(256) void mfma_xg(
    const unsigned short* __restrict__ Ah, const unsigned short* __restrict__ Al,
    const unsigned short* __restrict__ Bh, const unsigned short* __restrict__ Bl,
    float* __restrict__ part)
{
  __shared__ unsigned short s_ah[128 * 40];
  __shared__ unsigned short s_al[128 * 40];
  __shared__ unsigned short s_bh[128 * 40];
  __shared__ unsigned short s_bl[128 * 40];

  const int tid = threadIdx.x;
  const int col0 = blockIdx.x * 128;
  const int row0 = blockIdx.y * 128;
  const int kbase = blockIdx.z * 512;
  float* outp = part + (size_t)blockIdx.z * 1048576;

  const int wave = tid >> 6;
  const int lane = tid & 63;
  const int wr = wave >> 1, wc = wave & 1;
  const int quad = lane >> 4;
  const int l16 = lane & 15;

  f32x4 acc[4][4];
  #pragma unroll
  for (int i = 0; i < 4; ++i)
    #pragma unroll
    for (int j = 0; j < 4; ++j) acc[i][j] = f32x4{0.f, 0.f, 0.f, 0.f};

  for (int step = 0; step < 16; ++step) {
    const int koff = kbase + step * 32;
    // stage: 512 16B-chunks per buffer; thread does chunks tid, tid+256
    #pragma unroll
    for (int c = tid; c < 512; c += 256) {
      int row = c >> 2, kc = (c & 3) * 8;
      int4 va = *(const int4*)(Ah + (size_t)(row0 + row) * 4096 + koff + kc);
      int4 vb = *(const int4*)(Al + (size_t)(row0 + row) * 4096 + koff + kc);
      int4 vc = *(const int4*)(Bh + (size_t)(col0 + row) * 4096 + koff + kc);
      int4 vd = *(const int4*)(Bl + (size_t)(col0 + row) * 4096 + koff + kc);
      *(int4*)&s_ah[row * 40 + kc] = va;
      *(int4*)&s_al[row * 40 + kc] = vb;
      *(int4*)&s_bh[row * 40 + kc] = vc;
      *(int4*)&s_bl[row * 40 + kc] = vd;
    }
    __syncthreads();

    bf16x8 arh[4], arl[4];
    #pragma unroll
    for (int i = 0; i < 4; ++i) {
      int m = wr * 64 + i * 16 + l16;
      arh[i] = __builtin_bit_cast(bf16x8, *(const int4*)&s_ah[m * 40 + quad * 8]);
      arl[i] = __builtin_bit_cast(bf16x8, *(const int4*)&s_al[m * 40 + quad * 8]);
    }
    #pragma unroll
    for (int j = 0; j < 4; ++j) {
      int nn = wc * 64 + j * 16 + l16;
      bf16x8 brh = __builtin_bit_cast(bf16x8, *(const int4*)&s_bh[nn * 40 + quad * 8]);
      bf16x8 brl = __builtin_bit_cast(bf16x8, *(const int4*)&s_bl[nn * 40 + quad * 8]);
      #pragma unroll
      for (int i = 0; i < 4; ++i) {
        acc[i][j] = __builtin_amdgcn_mfma_f32_16x16x32_bf16(arh[i], brh, acc[i][j], 0, 0, 0);
        acc[i][j] = __builtin_amdgcn_mfma_f32_16x16x32_bf16(arh[i], brl, acc[i][j], 0, 0, 0);
        acc[i][j] = __builtin_amdgcn_mfma_f32_16x16x32_bf16(arl[i], brh, acc[i][j], 0, 0, 0);
      }
    }
    __syncthreads();
  }

  // C/D layout: col = lane&15, row = quad*4 + reg  [m89-verified]
  #pragma unroll
  for (int i = 0; i < 4; ++i)
    #pragma unroll
    for (int j = 0; j < 4; ++j) {
      int row = row0 + wr * 64 + i * 16 + quad * 4;
      int col = col0 + wc * 64 + j * 16 + l16;
      #pragma unroll
      for (int r = 0; r < 4; ++r)
        outp[(size_t)(row + r) * 1024 + col] = acc[i][j][r];
    }
}

// xg = sum_z p[z] + (b_ih + b_hh)
__global__ __launch_bounds__(256) void reduce_xg(
    const float* __restrict__ p, const float* __restrict__ b_ih,
    const float* __restrict__ b_hh, float* __restrict__ xg)
{
  int i = blockIdx.x * 256 + threadIdx.x;
  float4 s = {0.f, 0.f, 0.f, 0.f};
  #pragma unroll
  for (int z = 0; z < 8; ++z) {
    float4 a = ((const float4*)p)[(size_t)z * 262144 + i];
    s.x += a.x; s.y += a.y; s.z += a.z; s.w += a.w;
  }
  int cb = i & 255;
  float4 bi = ((const float4*)b_ih)[cb];
  float4 bh = ((const float4*)b_hh)[cb];
  float4 o;
  o.x = s.x + bi.x + bh.x;
  o.y = s.y + bi.y + bh.y;
  o.z = s.z + bi.z + bh.z;
  o.w = s.w + bi.w + bh.w;
  ((float4*)xg)[i] = o;
}

// ---------------- persistent LSTM recurrence ----------------
__global__ __launch_bounds__(1024) void lstm_kernel(
    const float* __restrict__ xg, const float* __restrict__ w_hh,
    float* __restrict__ hs, unsigned long long* __restrict__ hpair)
{
  const int b = blockIdx.x & 15;
  const int g = blockIdx.x >> 4;
  const int tid = threadIdx.x;
  const int r = tid >> 2;
  const int q = tid & 3;
  const int gate = r >> 6;
  const int jl = r & 63;
  const int j = g * 64 + jl;

  float4 wv[16];
  {
    const float4* wrow = (const float4*)(w_hh + ((size_t)(gate * 256 + j)) * 256 + q * 64);
    #pragma unroll
    for (int k = 0; k < 16; ++k) wv[k] = wrow[k];
  }

  __shared__ float s_h[4 * 72];
  __shared__ float s_gates[4][64];
  float c_reg = 0.f;

  for (int s = 0; s < 64; ++s) {
    float xv = 0.f;
    if (q == 0) xv = xg[(size_t)(s * 16 + b) * 1024 + gate * 256 + j];
    float gv = 0.f;
    if (s > 0) {
      if (tid < 256) {
        const unsigned long long* src = hpair + ((size_t)(s - 1) * 16 + b) * 256 + tid;
        unsigned long long pv;
        do {
          pv = __hip_atomic_load(src, __ATOMIC_RELAXED, __HIP_MEMORY_SCOPE_AGENT);
        } while ((unsigned int)(pv >> 32) != (unsigned int)s);
        s_h[(tid >> 6) * 72 + (tid & 63)] = __uint_as_float((unsigned int)pv);
      }
      __syncthreads();
      const float4* hp = (const float4*)&s_h[q * 72];
      float p = 0.f;
      #pragma unroll
      for (int k = 0; k < 16; ++k) {
        float4 h4 = hp[k];
        p = fmaf(h4.x, wv[k].x, p);
        p = fmaf(h4.y, wv[k].y, p);
        p = fmaf(h4.z, wv[k].z, p);
        p = fmaf(h4.w, wv[k].w, p);
      }
      p += __shfl_xor(p, 1);
      p += __shfl_xor(p, 2);
      gv = p;
    }
    if (q == 0) s_gates[gate][jl] = gv + xv;
    __syncthreads();
    if (tid < 64) {
      float gi = s_gates[0][tid], gf = s_gates[1][tid];
      float gg = s_gates[2][tid], go = s_gates[3][tid];
      float cn = sigmoidf_(gf) * c_reg + sigmoidf_(gi) * tanhf(gg);
      c_reg = cn;
      float hv = sigmoidf_(go) * tanhf(cn);
      hs[(size_t)s * 4096 + b * 256 + g * 64 + tid] = hv;
      unsigned long long pv =
          ((unsigned long long)(unsigned int)(s + 1) << 32) | __float_as_uint(hv);
      __hip_atomic_store(hpair + ((size_t)s * 16 + b) * 256 + g * 64 + tid, pv,
                         __ATOMIC_RELAXED, __HIP_MEMORY_SCOPE_AGENT);
    }
  }
}

// ---------------- classifier head ----------------
__global__ __launch_bounds__(64) void cls_kernel(
    const float* __restrict__ hs, const float* __restrict__ cw,
    const float* __restrict__ cb, float* __restrict__ out)
{
  const int id = blockIdx.x;
  const int b = id / 53;
  const int t = id % 53;
  const int s = 11 + t;
  const int lane = threadIdx.x;
  float4 hv = ((const float4*)(hs + (size_t)s * 4096 + b * 256))[lane];
  float4 wv = ((const float4*)cw)[lane];
  float p = hv.x * wv.x + hv.y * wv.y + hv.z * wv.z + hv.w * wv.w;
  #pragma unroll
  for (int off = 32; off >= 1; off >>= 1) p += __shfl_xor(p, off);
  if (lane == 0) out[id] = tanhf(p + cb[0]);
}

// ---------------------------------------------------------------------------
extern "C" void kernel_launch(void* const* d_in, const int* in_sizes, int n_in,
                              void* d_out, int out_size, void* d_ws, size_t ws_size,
                              hipStream_t stream)
{
  (void)in_sizes; (void)n_in; (void)out_size; (void)ws_size;
  const float* imgs = (const float*)d_in[0];
  const float* w_ih  = (const float*)d_in[31];
  const float* w_hh  = (const float*)d_in[32];
  const float* b_ih  = (const float*)d_in[33];
  const float* b_hh  = (const float*)d_in[34];
  const float* cls_w = (const float*)d_in[35];
  const float* cls_b = (const float*)d_in[36];
  float* out = (float*)d_out;

  // ws layout (floats): actA(16.78M: [0,8.39M) = 8 gemm partials,
  // [8.39M,16.78M) = bf16 splits Ah/Al/Bh/Bl as ushort) actB(16.78M feats)
  // xg(1.05M) hs(262K) hpair(524K u64) wf bias
  float* ws   = (float*)d_ws;
  float* actA = ws;
  float* actB = actA + 16777216;
  float* xg   = actB + 16777216;
  float* hs   = xg + 1048576;
  unsigned long long* hpair = (unsigned long long*)(hs + 262144);
  float* wfp  = hs + 262144 + 524288;
  static const int ocs[6] = {16, 16, 32, 32, 64, 64};
  static const int ics[6] = {3, 16, 16, 32, 32, 64};
  float* wf[6];
  size_t off = 0;
  for (int i = 0; i < 6; ++i) { wf[i] = wfp + off; off += (size_t)ocs[i] * ics[i] * 12; }
  float* biasp = wfp + off;
  float* bias[6];
  for (int i = 0; i < 6; ++i) bias[i] = biasp + i * 64;

  float* partials = actA;
  unsigned short* Ah = (unsigned short*)(actA + 8388608);
  unsigned short* Al = Ah + 4194304;
  unsigned short* Bh = Al + 4194304;
  unsigned short* Bl = Bh + 4194304;

  FoldPack fp;
  for (int i = 0; i < 6; ++i) {
    fp.w[i] = (const float*)d_in[1 + 5*i];
    fp.g[i] = (const float*)d_in[2 + 5*i];
    fp.b[i] = (const float*)d_in[3 + 5*i];
    fp.m[i] = (const float*)d_in[4 + 5*i];
    fp.v[i] = (const float*)d_in[5 + 5*i];
    fp.wf[i] = wf[i];
    fp.bias[i] = bias[i];
    fp.oc[i] = ocs[i];
    fp.ic[i] = ics[i];
  }
  fold_all<<<dim3(8, 6), 256, 0, stream>>>(fp);

  //                IC  OC  IH  IW  S  TP SPL ICS MW
  conv_bn_relu< 3, 16, 64, 64, 2,  4, 2, 1, 4><<<2048, 256, 0, stream>>>(imgs,  wf[0], bias[0], actA);
  conv_bn_relu<16, 16, 32, 32, 1,  4, 4, 1, 4><<<4096, 256, 0, stream>>>(actA, wf[1], bias[1], actB);
  conv_bn_relu<16, 32, 32, 32, 2,  4, 1, 1, 2><<<1024, 256, 0, stream>>>(actB, wf[2], bias[2], actA);
  conv_bn_relu<32, 32, 16, 16, 1,  4, 1, 1, 3><<<1024, 256, 0, stream>>>(actA, wf[3], bias[3], actB);
  conv_bn_relu<32, 64, 16, 16, 2,  2, 1, 2, 2><<<1024, 256, 0, stream>>>(actB, wf[4], bias[4], actA);
  conv_bn_relu<64, 64,  8,  8, 1,  4, 1, 4, 2><<<1024, 256, 0, stream>>>(actA, wf[5], bias[5], actB);

  split_a<<<4096, 256, 0, stream>>>(actB, Ah, Al);
  split_b<<<4096, 256, 0, stream>>>(w_ih, Bh, Bl);
  mfma_xg<<<dim3(8, 8, 8), 256, 0, stream>>>(Ah, Al, Bh, Bl, partials);
  reduce_xg<<<1024, 256, 0, stream>>>(partials, b_ih, b_hh, xg);
  lstm_kernel<<<64, 1024, 0, stream>>>(xg, w_hh, hs, hpair);
  cls_kernel<<<848, 64, 0, stream>>>(hs, cls_w, cls_b, out);
}

// Round 9
// 490.275 us; speedup vs baseline: 1.6298x; 1.4408x over previous
//
#include <hip/hip_runtime.h>
#include <cmath>

// ---------------------------------------------------------------------------
// 6x (conv3x3+BN+ReLU) -> LSTM(4096->256) over S=64 -> tanh(linear).
// R9: convs L1..L5 ported to split-bf16 MFMA implicit-GEMM (hh+hl+lh, the
// 3-stream split proven at absmax 3e-8 in R8's GEMM). A=packed weights from
// global (scalar-free, L2-cached, zero LDS cost); B=input in LDS as NHWC
// bf16 hi/lo, k=tap*IC+ic so a B-frag is ONE ds_read_b128. K=144 layers
// padded to 160 via zero tap-9 (extra zero LDS row; zero weights). L0 (K=27)
// stays fp32. fp32 VALU floored convs at 128us; MFMA puts them at ~40us.
// ---------------------------------------------------------------------------

typedef __attribute__((ext_vector_type(8))) __bf16 bf16x8;
typedef __attribute__((ext_vector_type(4))) float f32x4;

__device__ __forceinline__ float sigmoidf_(float x) { return 1.f / (1.f + expf(-x)); }

__device__ __forceinline__ unsigned short f2bf(float f) {   // RNE
  unsigned u = __float_as_uint(f);
  unsigned r = (u + 0x7fffu + ((u >> 16) & 1u)) >> 16;
  return (unsigned short)r;
}
__device__ __forceinline__ float bf2f(unsigned short h) {
  return __uint_as_float(((unsigned)h) << 16);
}

// ---------------- fold BN into conv weights (fp32 path + bias) ----------
struct FoldPack {
  const float *w[6], *g[6], *b[6], *m[6], *v[6];
  float *wf[6], *bias[6];
  int oc[6], ic[6];
};

__global__ __launch_bounds__(256) void fold_all(FoldPack p) {
  const int layer = blockIdx.y;
  const int OC = p.oc[layer], IC = p.ic[layer];
  const int total = OC * IC * 9;
  const float* w = p.w[layer];
  float* wf = p.wf[layer];
  for (int i = blockIdx.x * 256 + threadIdx.x; i < total; i += gridDim.x * 256) {
    int oc = i / (IC * 9);
    int r  = i % (IC * 9);
    int ic = r / 9;
    int k  = r % 9;
    int ky = k / 3, kx = k % 3;
    float inv = p.g[layer][oc] / sqrtf(p.v[layer][oc] + 1e-5f);
    wf[(((ic * 3 + ky) * OC) + oc) * 4 + kx] = w[i] * inv;
  }
  if (blockIdx.x == 0) {
    int i = threadIdx.x;
    if (i < OC) {
      float inv = p.g[layer][i] / sqrtf(p.v[layer][i] + 1e-5f);
      p.bias[layer][i] = p.b[layer][i] - p.m[layer][i] * inv;
    }
  }
}

// ---------------- pack BN-folded weights into MFMA A-frag layout ----------
// A[m=oc][k], k = tap*IC + ic (tap-major). Layout: [mt*KG+g][lane(64)][8]
// where lane -> (m = mt*16 + (lane&15), k = 32g + 8*(lane>>4) + j).
// k >= Kreal -> 0 (zero tap-9 padding for IC=16 layers). bf16 hi + lo.
struct PackPack {
  const float *w[5], *g[5], *v[5];
  unsigned short *wh[5], *wl[5];
  int ic[5], oc[5], kg[5], kreal[5];
};

__global__ __launch_bounds__(256) void pack_w(PackPack p) {
  const int layer = blockIdx.y;
  const int IC = p.ic[layer], KG = p.kg[layer], K = p.kreal[layer];
  const int MT = p.oc[layer] / 16;
  const int total = MT * KG * 512;
  for (int i = blockIdx.x * 256 + threadIdx.x; i < total; i += gridDim.x * 256) {
    int j = i & 7;
    int lane = (i >> 3) & 63;
    int gmt = i >> 9;               // = mt*KG + g
    int m = (gmt / KG) * 16 + (lane & 15);
    int k = 32 * (gmt % KG) + 8 * (lane >> 4) + j;
    float val = 0.f;
    if (k < K) {
      int tap = k / IC, ic = k % IC;
      int ky = tap / 3, kx = tap % 3;
      float inv = p.g[layer][m] / sqrtf(p.v[layer][m] + 1e-5f);
      val = p.w[layer][((m * IC + ic) * 3 + ky) * 3 + kx] * inv;
    }
    unsigned short h = f2bf(val);
    p.wh[layer][i] = h;
    p.wl[layer][i] = f2bf(val - bf2f(h));
  }
}

// ---------------- fp32 direct conv (L0 only: IC=3, K=27) ----------------
template<int IC, int OC, int IH, int IW, int STRIDE, int TPOS, int SPLITY,
         int ICS, int MINW>
__global__ __launch_bounds__(256, MINW) void conv_bn_relu(
    const float* __restrict__ in, const float* __restrict__ wf,
    const float* __restrict__ bias, float* __restrict__ out)
{
  constexpr int OH = IH / STRIDE, OW = IW / STRIDE;
  constexpr int OHB = OH / SPLITY;
  constexpr int RIH = (SPLITY == 1) ? (IH + 2) : ((OHB - 1) * STRIDE + 3);
  constexpr int PIW = IW + 4;
  constexpr int PLANE = RIH * PIW;
  constexpr int NPOS = OHB * OW;
  constexpr int WPOS = NPOS / TPOS;
  constexpr int SLOT = WPOS * ICS;
  constexpr int GROUPS = 256 / SLOT;
  constexpr int TOC = OC / GROUPS;
  constexpr int CH = IC / ICS;
  constexpr int SPAN = (TPOS - 1) * STRIDE + 3;
  constexpr int NW = (SPAN + 3) / 4;
  constexpr int XSLOTS = OW / TPOS;
  static_assert(SLOT % 64 == 0 && GROUPS * SLOT == 256 && GROUPS * TOC == OC, "tiling");

  __shared__ float s_in[IC * PLANE];

  const int tid = threadIdx.x;
  const int n     = (SPLITY == 1) ? blockIdx.x : blockIdx.x / SPLITY;
  const int split = (SPLITY == 1) ? 0 : blockIdx.x % SPLITY;
  const int ry0 = split * OHB;
  const int r0  = ry0 * STRIDE - 1;

  for (int i = tid; i < IC * PLANE / 4; i += 256)
    ((float4*)s_in)[i] = float4{0.f, 0.f, 0.f, 0.f};
  __syncthreads();

  constexpr int ROWF4 = IW / 4;
  constexpr int NSTG = IC * RIH * ROWF4;
  for (int i = tid; i < NSTG; i += 256) {
    int rw  = i % ROWF4;
    int t   = i / ROWF4;
    int row = t % RIH;
    int ic  = t / RIH;
    int giy = r0 + row;
    if (giy >= 0 && giy < IH) {
      float4 v = *(const float4*)(in + ((size_t)(n * IC + ic) * IH + giy) * IW + rw * 4);
      float* dst = &s_in[(ic * RIH + row) * PIW + 1 + rw * 4];
      dst[0] = v.x; dst[1] = v.y; dst[2] = v.z; dst[3] = v.w;
    }
  }
  __syncthreads();

  const int group  = tid / SLOT;
  const int sl     = tid % SLOT;
  const int icq    = sl / WPOS;
  const int worker = sl % WPOS;
  const int oy  = worker / XSLOTS;
  const int ox0 = (worker % XSLOTS) * TPOS;
  const int xb  = ox0 * STRIDE;

  const int oc0u = __builtin_amdgcn_readfirstlane(group * TOC);
  const float4* wg = (const float4*)wf + oc0u;

  float acc[TOC][TPOS];
  #pragma unroll
  for (int a = 0; a < TOC; ++a)
    #pragma unroll
    for (int p = 0; p < TPOS; ++p) acc[a][p] = 0.f;

  for (int icl = 0; icl < CH; ++icl) {
    const int ic = icq * CH + icl;
    const float* sI = &s_in[ic * PLANE];
    #pragma unroll
    for (int ky = 0; ky < 3; ++ky) {
      float row[NW * 4];
      {
        const float4* rp = (const float4*)&sI[(oy * STRIDE + ky) * PIW + xb];
        #pragma unroll
        for (int w = 0; w < NW; ++w) {
          float4 t4 = rp[w];
          row[4*w+0] = t4.x; row[4*w+1] = t4.y;
          row[4*w+2] = t4.z; row[4*w+3] = t4.w;
        }
      }
      const float4* wrow = wg + (ic * 3 + ky) * OC;
      #pragma unroll
      for (int oc = 0; oc < TOC; ++oc) {
        float4 w4 = wrow[oc];
        #pragma unroll
        for (int p = 0; p < TPOS; ++p)
          acc[oc][p] = fmaf(row[p * STRIDE + 0], w4.x,
                       fmaf(row[p * STRIDE + 1], w4.y,
                       fmaf(row[p * STRIDE + 2], w4.z, acc[oc][p])));
      }
    }
  }

  #pragma unroll
  for (int d = WPOS; d < SLOT; d <<= 1)
    #pragma unroll
    for (int oc = 0; oc < TOC; ++oc)
      #pragma unroll
      for (int p = 0; p < TPOS; ++p)
        acc[oc][p] += __shfl_xor(acc[oc][p], d);

  if (icq == 0) {
    float* outN = out + (size_t)n * (OC * OH * OW);
    #pragma unroll
    for (int oc = 0; oc < TOC; ++oc) {
      const float bb = bias[oc0u + oc];
      float* op = outN + ((size_t)(oc0u + oc) * OH + (ry0 + oy)) * OW + ox0;
      #pragma unroll
      for (int vq = 0; vq < TPOS / 4; ++vq) {
        float4 val;
        val.x = fmaxf(acc[oc][vq*4+0] + bb, 0.f);
        val.y = fmaxf(acc[oc][vq*4+1] + bb, 0.f);
        val.z = fmaxf(acc[oc][vq*4+2] + bb, 0.f);
        val.w = fmaxf(acc[oc][vq*4+3] + bb, 0.f);
        *(float4*)(op + vq * 4) = val;
      }
    }
  }
}

// ---------------- MFMA implicit-GEMM conv (L1..L5) ----------------
// M=OC (A=packed weights, global), N=positions (B=input, LDS NHWC bf16 h/l),
// K=IC*9 (padded to KG*32). C row=oc (quad*4+reg), col=pos (lane&15).
template<int IC, int OC, int IH, int IW, int STRIDE, int SPLITY, int KG, int ZROW>
__global__ __launch_bounds__(256, 2) void conv_mfma(
    const float* __restrict__ in, const unsigned short* __restrict__ Ah,
    const unsigned short* __restrict__ Al, const float* __restrict__ bias,
    float* __restrict__ out)
{
  constexpr int OH = IH / STRIDE, OW = IW / STRIDE;
  constexpr int OHB = OH / SPLITY;
  constexpr int N = OHB * OW;
  constexpr int NT = N / 16;
  constexpr int NTW = NT / 4;              // n-tiles per wave
  constexpr int MT = OC / 16;
  constexpr int ICP = IC + 8;              // bank-skew pad (2-way worst, stride1)
  constexpr int PW = IW + 3;
  constexpr int PH = (OHB - 1) * STRIDE + 3 + ZROW;
  constexpr int SZ = ((PH * PW * ICP + 7) / 8) * 8;
  static_assert(NT % 4 == 0, "nt");

  __shared__ unsigned short s_h[SZ];
  __shared__ unsigned short s_l[SZ];

  const int tid = threadIdx.x;
  const int n     = (SPLITY == 1) ? blockIdx.x : blockIdx.x / SPLITY;
  const int split = (SPLITY == 1) ? 0 : blockIdx.x % SPLITY;
  const int y0 = split * OHB;
  const int r0 = y0 * STRIDE - 1;

  // zero both planes (halo + K-pad rows must be finite-zero)
  for (int i = tid * 8; i < SZ; i += 2048) {
    *(int4*)&s_h[i] = int4{0, 0, 0, 0};
    *(int4*)&s_l[i] = int4{0, 0, 0, 0};
  }
  __syncthreads();

  // stage NCHW fp32 -> NHWC bf16 hi/lo (rows clipped at runtime)
  constexpr int ROWF4 = IW / 4;
  for (int i = tid; i < IC * PH * ROWF4; i += 256) {
    int rw  = i % ROWF4;
    int t   = i / ROWF4;
    int row = t % PH;
    int ic  = t / PH;
    int giy = r0 + row;
    if (giy >= 0 && giy < IH) {
      float4 v = *(const float4*)(in + ((size_t)(n * IC + ic) * IH + giy) * IW + rw * 4);
      int base = (row * PW + rw * 4 + 1) * ICP + ic;
      float vv[4] = {v.x, v.y, v.z, v.w};
      #pragma unroll
      for (int e = 0; e < 4; ++e) {
        unsigned short h = f2bf(vv[e]);
        s_h[base + e * ICP] = h;
        s_l[base + e * ICP] = f2bf(vv[e] - bf2f(h));
      }
    }
  }
  __syncthreads();

  const int wave = tid >> 6;
  const int lane = tid & 63;
  const int l16  = lane & 15;
  const int quad = lane >> 4;

  f32x4 acc[MT][NTW];
  #pragma unroll
  for (int mt = 0; mt < MT; ++mt)
    #pragma unroll
    for (int nt = 0; nt < NTW; ++nt) acc[mt][nt] = f32x4{0.f, 0.f, 0.f, 0.f};

  for (int g = 0; g < KG; ++g) {
    // per-lane k decomposition (IC pow2 -> shifts; tap<=9)
    const int k0 = 32 * g + 8 * quad;
    const int tap = k0 / IC;
    const int ic0 = k0 % IC;
    const int ky = tap / 3;
    const int kx = tap - ky * 3;
    bf16x8 afh[MT], afl[MT];
    #pragma unroll
    for (int mt = 0; mt < MT; ++mt) {
      size_t wo = ((size_t)(mt * KG + g) * 64 + lane) * 8;
      afh[mt] = __builtin_bit_cast(bf16x8, *(const int4*)(Ah + wo));
      afl[mt] = __builtin_bit_cast(bf16x8, *(const int4*)(Al + wo));
    }
    #pragma unroll
    for (int nt = 0; nt < NTW; ++nt) {
      int p = (wave * NTW + nt) * 16 + l16;
      int py = p / OW, px = p % OW;
      int addr = ((py * STRIDE + ky) * PW + px * STRIDE + kx) * ICP + ic0;
      bf16x8 bh = __builtin_bit_cast(bf16x8, *(const int4*)&s_h[addr]);
      bf16x8 bl = __builtin_bit_cast(bf16x8, *(const int4*)&s_l[addr]);
      #pragma unroll
      for (int mt = 0; mt < MT; ++mt) {
        acc[mt][nt] = __builtin_amdgcn_mfma_f32_16x16x32_bf16(afh[mt], bh, acc[mt][nt], 0, 0, 0);
        acc[mt][nt] = __builtin_amdgcn_mfma_f32_16x16x32_bf16(afh[mt], bl, acc[mt][nt], 0, 0, 0);
        acc[mt][nt] = __builtin_amdgcn_mfma_f32_16x16x32_bf16(afl[mt], bh, acc[mt][nt], 0, 0, 0);
      }
    }
  }

  // epilogue: bias + relu, NCHW store (col=pos coalesced per oc-row)
  #pragma unroll
  for (int mt = 0; mt < MT; ++mt)
    #pragma unroll
    for (int nt = 0; nt < NTW; ++nt) {
      int p = (wave * NTW + nt) * 16 + l16;
      int py = p / OW, px = p % OW;
      #pragma unroll
      for (int r = 0; r < 4; ++r) {
        int oc = mt * 16 + quad * 4 + r;
        float v = acc[mt][nt][r] + bias[oc];
        out[((size_t)(n * OC + oc) * OH + y0 + py) * OW + px] = fmaxf(v, 0.f);
      }
    }
}

// ---------------- bf16 hi/lo split prepass (GEMM inputs) ----------------
__global__ __launch_bounds__(256) void split_a(
    const float* __restrict__ feats, unsigned short* __restrict__ ah,
    unsigned short* __restrict__ al)
{
  int i4 = blockIdx.x * 256 + threadIdx.x;
  int e = i4 * 4;
  int n = e >> 12;
  int k = e & 4095;
  int r = (n & 63) * 16 + (n >> 6);
  float4 v = ((const float4*)feats)[i4];
  ushort4 h, l;
  h.x = f2bf(v.x); l.x = f2bf(v.x - bf2f(h.x));
  h.y = f2bf(v.y); l.y = f2bf(v.y - bf2f(h.y));
  h.z = f2bf(v.z); l.z = f2bf(v.z - bf2f(h.z));
  h.w = f2bf(v.w); l.w = f2bf(v.w - bf2f(h.w));
  *(ushort4*)(ah + (size_t)r * 4096 + k) = h;
  *(ushort4*)(al + (size_t)r * 4096 + k) = l;
}

__global__ __launch_bounds__(256) void split_b(
    const float* __restrict__ w_ih, unsigned short* __restrict__ bh,
    unsigned short* __restrict__ bl)
{
  int i4 = blockIdx.x * 256 + threadIdx.x;
  float4 v = ((const float4*)w_ih)[i4];
  ushort4 h, l;
  h.x = f2bf(v.x); l.x = f2bf(v.x - bf2f(h.x));
  h.y = f2bf(v.y); l.y = f2bf(v.y - bf2f(h.y));
  h.z = f2bf(v.z); l.z = f2bf(v.z - bf2f(h.z));
  h.w = f2bf(v.w); l.w = f2bf(v.w - bf2f(h.w));
  ((ushort4*)bh)[i4] = h;
  ((ushort4*)bl)[i4] = l;
}

// ---------------- Xg partials: bf16 split-MFMA GEMM ----------------
__global__ __launch_bounds__(256) void mfma_xg(
    const unsigned short* __restrict__ Ah, const unsigned short* __restrict__ Al,
    const unsigned short* __restrict__ Bh, const unsigned short* __restrict__ Bl,
    float* __restrict__ part)
{
  __shared__ unsigned short s_ah[128 * 40];
  __shared__ unsigned short s_al[128 * 40];
  __shared__ unsigned short s_bh[128 * 40];
  __shared__ unsigned short s_bl[128 * 40];

  const int tid = threadIdx.x;
  const int col0 = blockIdx.x * 128;
  const int row0 = blockIdx.y * 128;
  const int kbase = blockIdx.z * 512;
  float* outp = part + (size_t)blockIdx.z * 1048576;

  const int wave = tid >> 6;
  const int lane = tid & 63;
  const int wr = wave >> 1, wc = wave & 1;
  const int quad = lane >> 4;
  const int l16 = lane & 15;

  f32x4 acc[4][4];
  #pragma unroll
  for (int i = 0; i < 4; ++i)
    #pragma unroll
    for (int j = 0; j < 4; ++j) acc[i][j] = f32x4{0.f, 0.f, 0.f, 0.f};

  for (int step = 0; step < 16; ++step) {
    const int koff = kbase + step * 32;
    #pragma unroll
    for (int c = tid; c < 512; c += 256) {
      int row = c >> 2, kc = (c & 3) * 8;
      int4 va = *(const int4*)(Ah + (size_t)(row0 + row) * 4096 + koff + kc);
      int4 vb = *(const int4*)(Al + (size_t)(row0 + row) * 4096 + koff + kc);
      int4 vc = *(const int4*)(Bh + (size_t)(col0 + row) * 4096 + koff + kc);
      int4 vd = *(const int4*)(Bl + (size_t)(col0 + row) * 4096 + koff + kc);
      *(int4*)&s_ah[row * 40 + kc] = va;
      *(int4*)&s_al[row * 40 + kc] = vb;
      *(int4*)&s_bh[row * 40 + kc] = vc;
      *(int4*)&s_bl[row * 40 + kc] = vd;
    }
    __syncthreads();

    bf16x8 arh[4], arl[4];
    #pragma unroll
    for (int i = 0; i < 4; ++i) {
      int m = wr * 64 + i * 16 + l16;
      arh[i] = __builtin_bit_cast(bf16x8, *(const int4*)&s_ah[m * 40 + quad * 8]);
      arl[i] = __builtin_bit_cast(bf16x8, *(const int4*)&s_al[m * 40 + quad * 8]);
    }
    #pragma unroll
    for (int j = 0; j < 4; ++j) {
      int nn = wc * 64 + j * 16 + l16;
      bf16x8 brh = __builtin_bit_cast(bf16x8, *(const int4*)&s_bh[nn * 40 + quad * 8]);
      bf16x8 brl = __builtin_bit_cast(bf16x8, *(const int4*)&s_bl[nn * 40 + quad * 8]);
      #pragma unroll
      for (int i = 0; i < 4; ++i) {
        acc[i][j] = __builtin_amdgcn_mfma_f32_16x16x32_bf16(arh[i], brh, acc[i][j], 0, 0, 0);
        acc[i][j] = __builtin_amdgcn_mfma_f32_16x16x32_bf16(arh[i], brl, acc[i][j], 0, 0, 0);
        acc[i][j] = __builtin_amdgcn_mfma_f32_16x16x32_bf16(arl[i], brh, acc[i][j], 0, 0, 0);
      }
    }
    __syncthreads();
  }

  #pragma unroll
  for (int i = 0; i < 4; ++i)
    #pragma unroll
    for (int j = 0; j < 4; ++j) {
      int row = row0 + wr * 64 + i * 16 + quad * 4;
      int col = col0 + wc * 64 + j * 16 + l16;
      #pragma unroll
      for (int r = 0; r < 4; ++r)
        outp[(size_t)(row + r) * 1024 + col] = acc[i][j][r];
    }
}

// xg = sum_z p[z] + (b_ih + b_hh)
__global__ __launch_bounds__(256) void reduce_xg(
    const float* __restrict__ p, const float* __restrict__ b_ih,
    const float* __restrict__ b_hh, float* __restrict__ xg)
{
  int i = blockIdx.x * 256 + threadIdx.x;
  float4 s = {0.f, 0.f, 0.f, 0.f};
  #pragma unroll
  for (int z = 0; z < 8; ++z) {
    float4 a = ((const float4*)p)[(size_t)z * 262144 + i];
    s.x += a.x; s.y += a.y; s.z += a.z; s.w += a.w;
  }
  int cb = i & 255;
  float4 bi = ((const float4*)b_ih)[cb];
  float4 bh = ((const float4*)b_hh)[cb];
  float4 o;
  o.x = s.x + bi.x + bh.x;
  o.y = s.y + bi.y + bh.y;
  o.z = s.z + bi.z + bh.z;
  o.w = s.w + bi.w + bh.w;
  ((float4*)xg)[i] = o;
}

// ---------------- persistent LSTM recurrence ----------------
__global__ __launch_bounds__(1024) void lstm_kernel(
    const float* __restrict__ xg, const float* __restrict__ w_hh,
    float* __restrict__ hs, unsigned long long* __restrict__ hpair)
{
  const int b = blockIdx.x & 15;
  const int g = blockIdx.x >> 4;
  const int tid = threadIdx.x;
  const int r = tid >> 2;
  const int q = tid & 3;
  const int gate = r >> 6;
  const int jl = r & 63;
  const int j = g * 64 + jl;

  float4 wv[16];
  {
    const float4* wrow = (const float4*)(w_hh + ((size_t)(gate * 256 + j)) * 256 + q * 64);
    #pragma unroll
    for (int k = 0; k < 16; ++k) wv[k] = wrow[k];
  }

  __shared__ float s_h[4 * 72];
  __shared__ float s_gates[4][64];
  float c_reg = 0.f;

  for (int s = 0; s < 64; ++s) {
    float xv = 0.f;
    if (q == 0) xv = xg[(size_t)(s * 16 + b) * 1024 + gate * 256 + j];
    float gv = 0.f;
    if (s > 0) {
      if (tid < 256) {
        const unsigned long long* src = hpair + ((size_t)(s - 1) * 16 + b) * 256 + tid;
        unsigned long long pv;
        do {
          pv = __hip_atomic_load(src, __ATOMIC_RELAXED, __HIP_MEMORY_SCOPE_AGENT);
        } while ((unsigned int)(pv >> 32) != (unsigned int)s);
        s_h[(tid >> 6) * 72 + (tid & 63)] = __uint_as_float((unsigned int)pv);
      }
      __syncthreads();
      const float4* hp = (const float4*)&s_h[q * 72];
      float p = 0.f;
      #pragma unroll
      for (int k = 0; k < 16; ++k) {
        float4 h4 = hp[k];
        p = fmaf(h4.x, wv[k].x, p);
        p = fmaf(h4.y, wv[k].y, p);
        p = fmaf(h4.z, wv[k].z, p);
        p = fmaf(h4.w, wv[k].w, p);
      }
      p += __shfl_xor(p, 1);
      p += __shfl_xor(p, 2);
      gv = p;
    }
    if (q == 0) s_gates[gate][jl] = gv + xv;
    __syncthreads();
    if (tid < 64) {
      float gi = s_gates[0][tid], gf = s_gates[1][tid];
      float gg = s_gates[2][tid], go = s_gates[3][tid];
      float cn = sigmoidf_(gf) * c_reg + sigmoidf_(gi) * tanhf(gg);
      c_reg = cn;
      float hv = sigmoidf_(go) * tanhf(cn);
      hs[(size_t)s * 4096 + b * 256 + g * 64 + tid] = hv;
      unsigned long long pv =
          ((unsigned long long)(unsigned int)(s + 1) << 32) | __float_as_uint(hv);
      __hip_atomic_store(hpair + ((size_t)s * 16 + b) * 256 + g * 64 + tid, pv,
                         __ATOMIC_RELAXED, __HIP_MEMORY_SCOPE_AGENT);
    }
  }
}

// ---------------- classifier head ----------------
__global__ __launch_bounds__(64) void cls_kernel(
    const float* __restrict__ hs, const float* __restrict__ cw,
    const float* __restrict__ cb, float* __restrict__ out)
{
  const int id = blockIdx.x;
  const int b = id / 53;
  const int t = id % 53;
  const int s = 11 + t;
  const int lane = threadIdx.x;
  float4 hv = ((const float4*)(hs + (size_t)s * 4096 + b * 256))[lane];
  float4 wv = ((const float4*)cw)[lane];
  float p = hv.x * wv.x + hv.y * wv.y + hv.z * wv.z + hv.w * wv.w;
  #pragma unroll
  for (int off = 32; off >= 1; off >>= 1) p += __shfl_xor(p, off);
  if (lane == 0) out[id] = tanhf(p + cb[0]);
}

// ---------------------------------------------------------------------------
extern "C" void kernel_launch(void* const* d_in, const int* in_sizes, int n_in,
                              void* d_out, int out_size, void* d_ws, size_t ws_size,
                              hipStream_t stream)
{
  (void)in_sizes; (void)n_in; (void)out_size; (void)ws_size;
  const float* imgs = (const float*)d_in[0];
  const float* w_ih  = (const float*)d_in[31];
  const float* w_hh  = (const float*)d_in[32];
  const float* b_ih  = (const float*)d_in[33];
  const float* b_hh  = (const float*)d_in[34];
  const float* cls_w = (const float*)d_in[35];
  const float* cls_b = (const float*)d_in[36];
  float* out = (float*)d_out;

  float* ws   = (float*)d_ws;
  float* actA = ws;
  float* actB = actA + 16777216;
  float* xg   = actB + 16777216;
  float* hs   = xg + 1048576;
  unsigned long long* hpair = (unsigned long long*)(hs + 262144);
  float* wfp  = hs + 262144 + 524288;
  static const int ocs[6] = {16, 16, 32, 32, 64, 64};
  static const int ics[6] = {3, 16, 16, 32, 32, 64};
  float* wf[6];
  size_t off = 0;
  for (int i = 0; i < 6; ++i) { wf[i] = wfp + off; off += (size_t)ocs[i] * ics[i] * 12; }
  float* biasp = wfp + off;
  float* bias[6];
  for (int i = 0; i < 6; ++i) bias[i] = biasp + i * 64;

  // packed MFMA weights (L1..L5): sizes MT*KG*512 ushorts per plane
  static const int psz[5] = {2560, 5120, 9216, 18432, 36864};
  unsigned short* WH = (unsigned short*)(biasp + 6 * 64);
  unsigned short* WL = WH + 72192;
  unsigned short *wh[5], *wl[5];
  {
    int o = 0;
    for (int i = 0; i < 5; ++i) { wh[i] = WH + o; wl[i] = WL + o; o += psz[i]; }
  }

  float* partials = actA;       // reused post-conv
  unsigned short* Ah = (unsigned short*)(actA + 8388608);
  unsigned short* Al = Ah + 4194304;
  unsigned short* Bh = Al + 4194304;
  unsigned short* Bl = Bh + 4194304;

  FoldPack fp;
  for (int i = 0; i < 6; ++i) {
    fp.w[i] = (const float*)d_in[1 + 5*i];
    fp.g[i] = (const float*)d_in[2 + 5*i];
    fp.b[i] = (const float*)d_in[3 + 5*i];
    fp.m[i] = (const float*)d_in[4 + 5*i];
    fp.v[i] = (const float*)d_in[5 + 5*i];
    fp.wf[i] = wf[i];
    fp.bias[i] = bias[i];
    fp.oc[i] = ocs[i];
    fp.ic[i] = ics[i];
  }
  fold_all<<<dim3(8, 6), 256, 0, stream>>>(fp);

  PackPack pp;
  static const int kgs[5] = {5, 5, 9, 9, 18};
  static const int krs[5] = {144, 144, 288, 288, 576};
  for (int i = 0; i < 5; ++i) {
    pp.w[i] = (const float*)d_in[1 + 5*(i+1)];
    pp.g[i] = (const float*)d_in[2 + 5*(i+1)];
    pp.v[i] = (const float*)d_in[5 + 5*(i+1)];
    pp.wh[i] = wh[i];
    pp.wl[i] = wl[i];
    pp.ic[i] = ics[i+1];
    pp.oc[i] = ocs[i+1];
    pp.kg[i] = kgs[i];
    pp.kreal[i] = krs[i];
  }
  pack_w<<<dim3(36, 5), 256, 0, stream>>>(pp);

  // L0 fp32 direct conv
  conv_bn_relu<3, 16, 64, 64, 2, 4, 2, 1, 4><<<2048, 256, 0, stream>>>(imgs, wf[0], bias[0], actA);
  //            IC  OC  IH  IW  S SPL KG ZR
  conv_mfma<16, 16, 32, 32, 1, 4, 5, 1><<<4096, 256, 0, stream>>>(actA, wh[0], wl[0], bias[1], actB);
  conv_mfma<16, 32, 32, 32, 2, 4, 5, 1><<<4096, 256, 0, stream>>>(actB, wh[1], wl[1], bias[2], actA);
  conv_mfma<32, 32, 16, 16, 1, 1, 9, 0><<<1024, 256, 0, stream>>>(actA, wh[2], wl[2], bias[3], actB);
  conv_mfma<32, 64, 16, 16, 2, 1, 9, 0><<<1024, 256, 0, stream>>>(actB, wh[3], wl[3], bias[4], actA);
  conv_mfma<64, 64,  8,  8, 1, 1, 18, 0><<<1024, 256, 0, stream>>>(actA, wh[4], wl[4], bias[5], actB);

  split_a<<<4096, 256, 0, stream>>>(actB, Ah, Al);
  split_b<<<4096, 256, 0, stream>>>(w_ih, Bh, Bl);
  mfma_xg<<<dim3(8, 8, 8), 256, 0, stream>>>(Ah, Al, Bh, Bl, partials);
  reduce_xg<<<1024, 256, 0, stream>>>(partials, b_ih, b_hh, xg);
  lstm_kernel<<<64, 1024, 0, stream>>>(xg, w_hh, hs, hpair);
  cls_kernel<<<848, 64, 0, stream>>>(hs, cls_w, cls_b, out);
}